// Round 1
// baseline (484.585 us; speedup 1.0000x reference)
//
#include <hip/hip_runtime.h>
#include <hip/hip_bf16.h>

#define N_FEAT 128

// ---------------------------------------------------------------------------
// CSR build kernels
// ---------------------------------------------------------------------------
__global__ void k_count(const int* __restrict__ dst, int E, int* __restrict__ cnt) {
    int i = blockIdx.x * blockDim.x + threadIdx.x;
    if (i < E) atomicAdd(&cnt[dst[i]], 1);
}

__global__ void k_dis(const int* __restrict__ cnt, float* __restrict__ dis, int n) {
    int i = blockIdx.x * blockDim.x + threadIdx.x;
    if (i < n) dis[i] = rsqrtf((float)(cnt[i] + 1));  // +1 self loop; always > 0
}

__global__ void k_blocksum(const int* __restrict__ cnt, int n, int* __restrict__ partial) {
    __shared__ int sm[256];
    int tid = threadIdx.x;
    int i = blockIdx.x * 256 + tid;
    sm[tid] = (i < n) ? cnt[i] : 0;
    __syncthreads();
    for (int s = 128; s > 0; s >>= 1) {
        if (tid < s) sm[tid] += sm[tid + s];
        __syncthreads();
    }
    if (tid == 0) partial[blockIdx.x] = sm[0];
}

// single block; nb <= 256
__global__ void k_scanpartial(int* __restrict__ partial, int nb, int* __restrict__ rowptr, int n) {
    __shared__ int sm[256];
    int tid = threadIdx.x;
    int mine = (tid < nb) ? partial[tid] : 0;
    sm[tid] = mine;
    __syncthreads();
    for (int off = 1; off < 256; off <<= 1) {
        int v = (tid >= off) ? sm[tid - off] : 0;
        __syncthreads();
        sm[tid] += v;
        __syncthreads();
    }
    if (tid < nb) partial[tid] = sm[tid] - mine;  // exclusive
    if (tid == nb - 1) rowptr[n] = sm[tid];       // total = E
}

__global__ void k_scatterptr(const int* __restrict__ cnt, const int* __restrict__ partial,
                             int n, int* __restrict__ rowptr, int* __restrict__ cursor) {
    __shared__ int sm[256];
    int tid = threadIdx.x;
    int i = blockIdx.x * 256 + tid;
    int mine = (i < n) ? cnt[i] : 0;
    sm[tid] = mine;
    __syncthreads();
    for (int off = 1; off < 256; off <<= 1) {
        int v = (tid >= off) ? sm[tid - off] : 0;
        __syncthreads();
        sm[tid] += v;
        __syncthreads();
    }
    if (i < n) {
        int p = partial[blockIdx.x] + sm[tid] - mine;
        rowptr[i] = p;
        cursor[i] = p;
    }
}

__global__ void k_fill(const int* __restrict__ src, const int* __restrict__ dst, int E,
                       int* __restrict__ cursor, int* __restrict__ csr) {
    int i = blockIdx.x * blockDim.x + threadIdx.x;
    if (i < E) {
        int d = dst[i];
        int p = atomicAdd(&cursor[d], 1);
        csr[p] = src[i];
    }
}

// ---------------------------------------------------------------------------
// fp32 GEMM: Y[n,COLS] = X[n,128] @ W[128,COLS]   (no bias)
// block = 256 threads, 32 rows per block. W staged in LDS in two 64-row chunks.
// ---------------------------------------------------------------------------
template <int COLS>
__global__ __launch_bounds__(256) void gemm_xw(const float* __restrict__ X,
                                               const float* __restrict__ W,
                                               float* __restrict__ Y, int n) {
    __shared__ float sW[64 * COLS];
    __shared__ float sX[32 * 132];  // +4 pad per row
    const int tid = threadIdx.x;
    const int row0 = blockIdx.x * 32;

    // load X tile 32x128 (4096 floats = 1024 float4)
    {
        const float4* X4 = (const float4*)X;
#pragma unroll
        for (int i = 0; i < 4; ++i) {
            int idx = i * 256 + tid;  // 0..1023
            int r = idx >> 5;
            int c = idx & 31;
            int gr = row0 + r;
            float4 v = make_float4(0.f, 0.f, 0.f, 0.f);
            if (gr < n) v = X4[(size_t)gr * 32 + c];
            *(float4*)&sX[r * 132 + c * 4] = v;
        }
    }

    constexpr int CG = COLS / 4;         // 32 or 16 col groups
    constexpr int RSTEP = 256 / CG;      // 8 or 16
    constexpr int RPT = 32 / RSTEP;      // 4 or 2 rows per thread
    const int tx = tid % CG;
    const int ty = tid / CG;

    float4 acc[RPT];
#pragma unroll
    for (int i = 0; i < RPT; ++i) acc[i] = make_float4(0.f, 0.f, 0.f, 0.f);

    for (int kc = 0; kc < 128; kc += 64) {
        __syncthreads();  // protect sW reuse; also makes sX visible on first pass
        // load 64 x COLS chunk of W
        constexpr int WCH = (64 * COLS) / (256 * 4);
        const float4* Wg = (const float4*)(W + kc * COLS);
        float4* sW4 = (float4*)sW;
#pragma unroll
        for (int i = 0; i < WCH; ++i) sW4[i * 256 + tid] = Wg[i * 256 + tid];
        __syncthreads();

#pragma unroll 4
        for (int kk = 0; kk < 64; kk += 4) {
            float4 wv[4];
#pragma unroll
            for (int j = 0; j < 4; ++j)
                wv[j] = *(const float4*)&sW[(kk + j) * COLS + tx * 4];
#pragma unroll
            for (int i = 0; i < RPT; ++i) {
                float4 xv = *(const float4*)&sX[(ty + i * RSTEP) * 132 + kc + kk];
                acc[i].x += xv.x * wv[0].x + xv.y * wv[1].x + xv.z * wv[2].x + xv.w * wv[3].x;
                acc[i].y += xv.x * wv[0].y + xv.y * wv[1].y + xv.z * wv[2].y + xv.w * wv[3].y;
                acc[i].z += xv.x * wv[0].z + xv.y * wv[1].z + xv.z * wv[2].z + xv.w * wv[3].z;
                acc[i].w += xv.x * wv[0].w + xv.y * wv[1].w + xv.z * wv[2].w + xv.w * wv[3].w;
            }
        }
    }

#pragma unroll
    for (int i = 0; i < RPT; ++i) {
        int r = row0 + ty + i * RSTEP;
        if (r < n) *(float4*)&Y[(size_t)r * COLS + tx * 4] = acc[i];
    }
}

// ---------------------------------------------------------------------------
// Aggregation: out[v] = act( dv*(sum_{s in CSR[v]} dis[s]*H[s] + dv*H[v]) + b )
// one wave per node. COLS=128 -> float2/lane; COLS=64 -> float/lane (+norm).
// ---------------------------------------------------------------------------
template <int COLS, bool RELU, bool NORM>
__global__ __launch_bounds__(256) void agg(const float* __restrict__ H,
                                           const float* __restrict__ dis,
                                           const int* __restrict__ rowptr,
                                           const int* __restrict__ csr,
                                           const float* __restrict__ bias,
                                           float* __restrict__ out, int n) {
    const int wid = blockIdx.x * 4 + (threadIdx.x >> 6);
    const int lane = threadIdx.x & 63;
    if (wid >= n) return;
    const int v = wid;
    const float dv = dis[v];
    const int e0 = rowptr[v];
    const int e1 = rowptr[v + 1];

    if (COLS == 128) {
        float2 h0 = *((const float2*)(H + (size_t)v * 128) + lane);
        float ax = dv * h0.x, ay = dv * h0.y;
        int e = e0;
        for (; e + 1 < e1; e += 2) {
            int s0 = csr[e], s1 = csr[e + 1];
            float w0 = dis[s0], w1 = dis[s1];
            float2 ha = *((const float2*)(H + (size_t)s0 * 128) + lane);
            float2 hb = *((const float2*)(H + (size_t)s1 * 128) + lane);
            ax += w0 * ha.x + w1 * hb.x;
            ay += w0 * ha.y + w1 * hb.y;
        }
        if (e < e1) {
            int s0 = csr[e];
            float w0 = dis[s0];
            float2 ha = *((const float2*)(H + (size_t)s0 * 128) + lane);
            ax += w0 * ha.x;
            ay += w0 * ha.y;
        }
        float2 b = ((const float2*)bias)[lane];
        float rx = dv * ax + b.x;
        float ry = dv * ay + b.y;
        if (RELU) { rx = fmaxf(rx, 0.f); ry = fmaxf(ry, 0.f); }
        float2 r = make_float2(rx, ry);
        *((float2*)(out + (size_t)v * 128) + lane) = r;
    } else {
        float acc = dv * H[(size_t)v * 64 + lane];
        int e = e0;
        for (; e + 1 < e1; e += 2) {
            int s0 = csr[e], s1 = csr[e + 1];
            float w0 = dis[s0], w1 = dis[s1];
            acc += w0 * H[(size_t)s0 * 64 + lane] + w1 * H[(size_t)s1 * 64 + lane];
        }
        if (e < e1) {
            int s0 = csr[e];
            acc += dis[s0] * H[(size_t)s0 * 64 + lane];
        }
        float r = dv * acc + bias[lane];
        if (RELU) r = fmaxf(r, 0.f);
        if (NORM) {
            float ss = r * r;
#pragma unroll
            for (int m = 1; m < 64; m <<= 1) ss += __shfl_xor(ss, m, 64);
            r = r / fmaxf(sqrtf(ss), 1e-12f);
        }
        out[(size_t)v * 64 + lane] = r;
    }
}

// ---------------------------------------------------------------------------
// Target branch: BN(y) -> Linear(1,128) -> ReLU -> Linear(128,64) -> row norm
// one block (256 thr) per row; BN stats recomputed per block (cheap).
// ---------------------------------------------------------------------------
__global__ __launch_bounds__(256) void target_mlp(const float* __restrict__ y,
                                                  const float* __restrict__ gamma,
                                                  const float* __restrict__ beta,
                                                  const float* __restrict__ Wm1,
                                                  const float* __restrict__ bm1,
                                                  const float* __restrict__ Wm2,
                                                  const float* __restrict__ bm2,
                                                  float* __restrict__ out) {
    __shared__ float red[256];
    __shared__ float t1[128];
    __shared__ float s_mu, s_var;
    const int tid = threadIdx.x;
    float yv = y[tid];  // 256 values
    red[tid] = yv;
    __syncthreads();
    for (int s = 128; s > 0; s >>= 1) {
        if (tid < s) red[tid] += red[tid + s];
        __syncthreads();
    }
    if (tid == 0) s_mu = red[0] * (1.0f / 256.0f);
    __syncthreads();
    float mu = s_mu;
    float d = yv - mu;
    red[tid] = d * d;
    __syncthreads();
    for (int s = 128; s > 0; s >>= 1) {
        if (tid < s) red[tid] += red[tid + s];
        __syncthreads();
    }
    if (tid == 0) s_var = red[0] * (1.0f / 256.0f);
    __syncthreads();

    const int row = blockIdx.x;
    float yb = (y[row] - mu) * rsqrtf(s_var + 1e-5f) * gamma[0] + beta[0];
    if (tid < 128) t1[tid] = fmaxf(yb * Wm1[tid] + bm1[tid], 0.0f);
    __syncthreads();
    if (tid < 64) {
        float acc = bm2[tid];
#pragma unroll 8
        for (int c = 0; c < 128; ++c) acc += t1[c] * Wm2[c * 64 + tid];
        float ss = acc * acc;
#pragma unroll
        for (int m = 1; m < 64; m <<= 1) ss += __shfl_xor(ss, m, 64);
        out[row * 64 + tid] = acc / fmaxf(sqrtf(ss), 1e-12f);
    }
}

// ---------------------------------------------------------------------------
extern "C" void kernel_launch(void* const* d_in, const int* in_sizes, int n_in,
                              void* d_out, int out_size, void* d_ws, size_t ws_size,
                              hipStream_t stream) {
    const float* x     = (const float*)d_in[0];   // [n,128]
    const float* y     = (const float*)d_in[1];   // [256,1]
    const int*   edge  = (const int*)d_in[2];     // [2,E]
    const float* W1    = (const float*)d_in[3];
    const float* b1    = (const float*)d_in[4];
    const float* W2    = (const float*)d_in[5];
    const float* b2    = (const float*)d_in[6];
    const float* W3    = (const float*)d_in[7];
    const float* b3    = (const float*)d_in[8];
    const float* bng   = (const float*)d_in[9];
    const float* bnb   = (const float*)d_in[10];
    const float* Wm1   = (const float*)d_in[11];
    const float* bm1   = (const float*)d_in[12];
    const float* Wm2   = (const float*)d_in[13];
    const float* bm2   = (const float*)d_in[14];

    const int n = in_sizes[0] / 128;      // 50000
    const int E = in_sizes[2] / 2;        // 800000
    const int* src = edge;
    const int* dst = edge + E;

    // workspace carve-out (256B aligned)
    size_t off = 0;
    auto carve = [&](size_t bytes) {
        size_t p = off;
        off = (off + bytes + 255) & ~(size_t)255;
        return p;
    };
    char* ws = (char*)d_ws;
    int*   cnt     = (int*)(ws + carve((size_t)n * 4));
    int*   rowptr  = (int*)(ws + carve((size_t)(n + 1) * 4));
    int*   cursor  = (int*)(ws + carve((size_t)n * 4));
    int*   partial = (int*)(ws + carve(1024));
    int*   csr     = (int*)(ws + carve((size_t)E * 4));
    float* dis     = (float*)(ws + carve((size_t)n * 4));
    float* bufA    = (float*)(ws + carve((size_t)n * 128 * 4));
    float* bufB    = (float*)(ws + carve((size_t)n * 128 * 4));
    float* bufC    = (float*)(ws + carve((size_t)n * 64 * 4));
    (void)ws_size; (void)n_in; (void)out_size;

    float* x_emb = (float*)d_out;             // [n,64]
    float* y_emb = (float*)d_out + (size_t)n * 64;

    const int nb = (n + 255) / 256;  // 196 scan blocks

    hipMemsetAsync(cnt, 0, (size_t)n * 4, stream);
    k_count<<<(E + 255) / 256, 256, 0, stream>>>(dst, E, cnt);
    k_dis<<<(n + 255) / 256, 256, 0, stream>>>(cnt, dis, n);
    k_blocksum<<<nb, 256, 0, stream>>>(cnt, n, partial);
    k_scanpartial<<<1, 256, 0, stream>>>(partial, nb, rowptr, n);
    k_scatterptr<<<nb, 256, 0, stream>>>(cnt, partial, n, rowptr, cursor);
    k_fill<<<(E + 255) / 256, 256, 0, stream>>>(src, dst, E, cursor, csr);

    const int gemm_grid = (n + 31) / 32;
    const int agg_grid = (n + 3) / 4;

    gemm_xw<128><<<gemm_grid, 256, 0, stream>>>(x, W1, bufA, n);
    agg<128, true, false><<<agg_grid, 256, 0, stream>>>(bufA, dis, rowptr, csr, b1, bufB, n);
    gemm_xw<128><<<gemm_grid, 256, 0, stream>>>(bufB, W2, bufA, n);
    agg<128, true, false><<<agg_grid, 256, 0, stream>>>(bufA, dis, rowptr, csr, b2, bufB, n);
    gemm_xw<64><<<gemm_grid, 256, 0, stream>>>(bufB, W3, bufC, n);
    agg<64, false, true><<<agg_grid, 256, 0, stream>>>(bufC, dis, rowptr, csr, b3, x_emb, n);

    target_mlp<<<256, 256, 0, stream>>>(y, bng, bnb, Wm1, bm1, Wm2, bm2, y_emb);
}

// Round 2
// 427.812 us; speedup vs baseline: 1.1327x; 1.1327x over previous
//
#include <hip/hip_runtime.h>
#include <hip/hip_bf16.h>

// ---------------------------------------------------------------------------
// CSR build kernels
// ---------------------------------------------------------------------------
__global__ void k_count(const int* __restrict__ dst, int E, int* __restrict__ cnt) {
    int i = blockIdx.x * blockDim.x + threadIdx.x;
    if (i < E) atomicAdd(&cnt[dst[i]], 1);
}

__global__ void k_dis(const int* __restrict__ cnt, float* __restrict__ dis, int n) {
    int i = blockIdx.x * blockDim.x + threadIdx.x;
    if (i < n) dis[i] = rsqrtf((float)(cnt[i] + 1));  // +1 self loop; always > 0
}

__global__ void k_blocksum(const int* __restrict__ cnt, int n, int* __restrict__ partial) {
    __shared__ int sm[256];
    int tid = threadIdx.x;
    int i = blockIdx.x * 256 + tid;
    sm[tid] = (i < n) ? cnt[i] : 0;
    __syncthreads();
    for (int s = 128; s > 0; s >>= 1) {
        if (tid < s) sm[tid] += sm[tid + s];
        __syncthreads();
    }
    if (tid == 0) partial[blockIdx.x] = sm[0];
}

// single block; nb <= 256
__global__ void k_scanpartial(int* __restrict__ partial, int nb, int* __restrict__ rowptr, int n) {
    __shared__ int sm[256];
    int tid = threadIdx.x;
    int mine = (tid < nb) ? partial[tid] : 0;
    sm[tid] = mine;
    __syncthreads();
    for (int off = 1; off < 256; off <<= 1) {
        int v = (tid >= off) ? sm[tid - off] : 0;
        __syncthreads();
        sm[tid] += v;
        __syncthreads();
    }
    if (tid < nb) partial[tid] = sm[tid] - mine;  // exclusive
    if (tid == nb - 1) rowptr[n] = sm[tid];       // total = E
}

__global__ void k_scatterptr(const int* __restrict__ cnt, const int* __restrict__ partial,
                             int n, int* __restrict__ rowptr, int* __restrict__ cursor) {
    __shared__ int sm[256];
    int tid = threadIdx.x;
    int i = blockIdx.x * 256 + tid;
    int mine = (i < n) ? cnt[i] : 0;
    sm[tid] = mine;
    __syncthreads();
    for (int off = 1; off < 256; off <<= 1) {
        int v = (tid >= off) ? sm[tid - off] : 0;
        __syncthreads();
        sm[tid] += v;
        __syncthreads();
    }
    if (i < n) {
        int p = partial[blockIdx.x] + sm[tid] - mine;
        rowptr[i] = p;
        cursor[i] = p;
    }
}

// fill CSR adjacency + per-edge weight ew[e] = dis[src[e]]
__global__ void k_fill(const int* __restrict__ src, const int* __restrict__ dst, int E,
                       int* __restrict__ cursor, const float* __restrict__ dis,
                       int* __restrict__ csr, float* __restrict__ ew) {
    int i = blockIdx.x * blockDim.x + threadIdx.x;
    if (i < E) {
        int d = dst[i];
        int s = src[i];
        int p = atomicAdd(&cursor[d], 1);
        csr[p] = s;
        ew[p] = dis[s];
    }
}

// ---------------------------------------------------------------------------
// fp32 GEMM: Y[n,COLS] = X[n,128] @ W[128,COLS]   (no bias)
// ---------------------------------------------------------------------------
template <int COLS>
__global__ __launch_bounds__(256) void gemm_xw(const float* __restrict__ X,
                                               const float* __restrict__ W,
                                               float* __restrict__ Y, int n) {
    __shared__ float sW[64 * COLS];
    __shared__ float sX[32 * 132];  // +4 pad per row
    const int tid = threadIdx.x;
    const int row0 = blockIdx.x * 32;

    {
        const float4* X4 = (const float4*)X;
#pragma unroll
        for (int i = 0; i < 4; ++i) {
            int idx = i * 256 + tid;  // 0..1023
            int r = idx >> 5;
            int c = idx & 31;
            int gr = row0 + r;
            float4 v = make_float4(0.f, 0.f, 0.f, 0.f);
            if (gr < n) v = X4[(size_t)gr * 32 + c];
            *(float4*)&sX[r * 132 + c * 4] = v;
        }
    }

    constexpr int CG = COLS / 4;         // 32 or 16 col groups
    constexpr int RSTEP = 256 / CG;      // 8 or 16
    constexpr int RPT = 32 / RSTEP;      // 4 or 2 rows per thread
    const int tx = tid % CG;
    const int ty = tid / CG;

    float4 acc[RPT];
#pragma unroll
    for (int i = 0; i < RPT; ++i) acc[i] = make_float4(0.f, 0.f, 0.f, 0.f);

    for (int kc = 0; kc < 128; kc += 64) {
        __syncthreads();
        constexpr int WCH = (64 * COLS) / (256 * 4);
        const float4* Wg = (const float4*)(W + kc * COLS);
        float4* sW4 = (float4*)sW;
#pragma unroll
        for (int i = 0; i < WCH; ++i) sW4[i * 256 + tid] = Wg[i * 256 + tid];
        __syncthreads();

#pragma unroll 4
        for (int kk = 0; kk < 64; kk += 4) {
            float4 wv[4];
#pragma unroll
            for (int j = 0; j < 4; ++j)
                wv[j] = *(const float4*)&sW[(kk + j) * COLS + tx * 4];
#pragma unroll
            for (int i = 0; i < RPT; ++i) {
                float4 xv = *(const float4*)&sX[(ty + i * RSTEP) * 132 + kc + kk];
                acc[i].x += xv.x * wv[0].x + xv.y * wv[1].x + xv.z * wv[2].x + xv.w * wv[3].x;
                acc[i].y += xv.x * wv[0].y + xv.y * wv[1].y + xv.z * wv[2].y + xv.w * wv[3].y;
                acc[i].z += xv.x * wv[0].z + xv.y * wv[1].z + xv.z * wv[2].z + xv.w * wv[3].z;
                acc[i].w += xv.x * wv[0].w + xv.y * wv[1].w + xv.z * wv[2].w + xv.w * wv[3].w;
            }
        }
    }

#pragma unroll
    for (int i = 0; i < RPT; ++i) {
        int r = row0 + ty + i * RSTEP;
        if (r < n) *(float4*)&Y[(size_t)r * COLS + tx * 4] = acc[i];
    }
}

// ---------------------------------------------------------------------------
// Aggregation: out[v] = act( dv*(sum_e ew[e]*H[csr[e]] + dv*H[v]) + b )
// One wave per node. Edge indices/weights staged lane-parallel (one coalesced
// load per 64 edges), broadcast via readlane -> SGPR row base; 8 independent
// row gathers in flight per wave.
// ---------------------------------------------------------------------------
__device__ __forceinline__ float lane_bcast_f(float v, int j) {
    return __uint_as_float(__builtin_amdgcn_readlane(__float_as_uint(v), j));
}

template <int COLS, bool RELU, bool NORM>
__global__ __launch_bounds__(256) void agg(const float* __restrict__ H,
                                           const float* __restrict__ dis,
                                           const int* __restrict__ rowptr,
                                           const int* __restrict__ csr,
                                           const float* __restrict__ ew,
                                           const float* __restrict__ bias,
                                           float* __restrict__ out, int n) {
    const int wid = blockIdx.x * 4 + (threadIdx.x >> 6);
    const int lane = threadIdx.x & 63;
    if (wid >= n) return;
    const int v = wid;
    const float dv = dis[v];
    const int e0 = rowptr[v];
    const int e1 = rowptr[v + 1];

    if (COLS == 128) {
        const float2* H2 = (const float2*)H;
        float2 h0 = H2[(size_t)v * 64 + lane];
        float ax = dv * h0.x, ay = dv * h0.y;

        int e = e0;
        while (e < e1) {
            const int c = min(e1 - e, 64);
            int sidx = 0; float sw = 0.0f;
            if (lane < c) { sidx = csr[e + lane]; sw = ew[e + lane]; }
            int j = 0;
            for (; j + 8 <= c; j += 8) {
                float2 hv[8]; float w[8];
#pragma unroll
                for (int u = 0; u < 8; ++u) {
                    int s = __builtin_amdgcn_readlane(sidx, j + u);
                    w[u] = lane_bcast_f(sw, j + u);
                    hv[u] = H2[(size_t)s * 64 + lane];
                }
#pragma unroll
                for (int u = 0; u < 8; ++u) { ax += w[u] * hv[u].x; ay += w[u] * hv[u].y; }
            }
            for (; j < c; ++j) {
                int s = __builtin_amdgcn_readlane(sidx, j);
                float w = lane_bcast_f(sw, j);
                float2 hh = H2[(size_t)s * 64 + lane];
                ax += w * hh.x; ay += w * hh.y;
            }
            e += c;
        }

        float2 b = ((const float2*)bias)[lane];
        float rx = dv * ax + b.x;
        float ry = dv * ay + b.y;
        if (RELU) { rx = fmaxf(rx, 0.f); ry = fmaxf(ry, 0.f); }
        *((float2*)(out + (size_t)v * 128) + lane) = make_float2(rx, ry);
    } else {
        float acc = dv * H[(size_t)v * 64 + lane];

        int e = e0;
        while (e < e1) {
            const int c = min(e1 - e, 64);
            int sidx = 0; float sw = 0.0f;
            if (lane < c) { sidx = csr[e + lane]; sw = ew[e + lane]; }
            int j = 0;
            for (; j + 8 <= c; j += 8) {
                float hv[8]; float w[8];
#pragma unroll
                for (int u = 0; u < 8; ++u) {
                    int s = __builtin_amdgcn_readlane(sidx, j + u);
                    w[u] = lane_bcast_f(sw, j + u);
                    hv[u] = H[(size_t)s * 64 + lane];
                }
#pragma unroll
                for (int u = 0; u < 8; ++u) acc += w[u] * hv[u];
            }
            for (; j < c; ++j) {
                int s = __builtin_amdgcn_readlane(sidx, j);
                float w = lane_bcast_f(sw, j);
                acc += w * H[(size_t)s * 64 + lane];
            }
            e += c;
        }

        float r = dv * acc + bias[lane];
        if (RELU) r = fmaxf(r, 0.f);
        if (NORM) {
            float ss = r * r;
#pragma unroll
            for (int m = 1; m < 64; m <<= 1) ss += __shfl_xor(ss, m, 64);
            r = r / fmaxf(sqrtf(ss), 1e-12f);
        }
        out[(size_t)v * 64 + lane] = r;
    }
}

// ---------------------------------------------------------------------------
// Target branch: BN(y) -> Linear(1,128) -> ReLU -> Linear(128,64) -> row norm
// ---------------------------------------------------------------------------
__global__ __launch_bounds__(256) void target_mlp(const float* __restrict__ y,
                                                  const float* __restrict__ gamma,
                                                  const float* __restrict__ beta,
                                                  const float* __restrict__ Wm1,
                                                  const float* __restrict__ bm1,
                                                  const float* __restrict__ Wm2,
                                                  const float* __restrict__ bm2,
                                                  float* __restrict__ out) {
    __shared__ float red[256];
    __shared__ float t1[128];
    __shared__ float s_mu, s_var;
    const int tid = threadIdx.x;
    float yv = y[tid];  // 256 values
    red[tid] = yv;
    __syncthreads();
    for (int s = 128; s > 0; s >>= 1) {
        if (tid < s) red[tid] += red[tid + s];
        __syncthreads();
    }
    if (tid == 0) s_mu = red[0] * (1.0f / 256.0f);
    __syncthreads();
    float mu = s_mu;
    float d = yv - mu;
    red[tid] = d * d;
    __syncthreads();
    for (int s = 128; s > 0; s >>= 1) {
        if (tid < s) red[tid] += red[tid + s];
        __syncthreads();
    }
    if (tid == 0) s_var = red[0] * (1.0f / 256.0f);
    __syncthreads();

    const int row = blockIdx.x;
    float yb = (y[row] - mu) * rsqrtf(s_var + 1e-5f) * gamma[0] + beta[0];
    if (tid < 128) t1[tid] = fmaxf(yb * Wm1[tid] + bm1[tid], 0.0f);
    __syncthreads();
    if (tid < 64) {
        float acc = bm2[tid];
#pragma unroll 8
        for (int c = 0; c < 128; ++c) acc += t1[c] * Wm2[c * 64 + tid];
        float ss = acc * acc;
#pragma unroll
        for (int m = 1; m < 64; m <<= 1) ss += __shfl_xor(ss, m, 64);
        out[row * 64 + tid] = acc / fmaxf(sqrtf(ss), 1e-12f);
    }
}

// ---------------------------------------------------------------------------
extern "C" void kernel_launch(void* const* d_in, const int* in_sizes, int n_in,
                              void* d_out, int out_size, void* d_ws, size_t ws_size,
                              hipStream_t stream) {
    const float* x     = (const float*)d_in[0];   // [n,128]
    const float* y     = (const float*)d_in[1];   // [256,1]
    const int*   edge  = (const int*)d_in[2];     // [2,E]
    const float* W1    = (const float*)d_in[3];
    const float* b1    = (const float*)d_in[4];
    const float* W2    = (const float*)d_in[5];
    const float* b2    = (const float*)d_in[6];
    const float* W3    = (const float*)d_in[7];
    const float* b3    = (const float*)d_in[8];
    const float* bng   = (const float*)d_in[9];
    const float* bnb   = (const float*)d_in[10];
    const float* Wm1   = (const float*)d_in[11];
    const float* bm1   = (const float*)d_in[12];
    const float* Wm2   = (const float*)d_in[13];
    const float* bm2   = (const float*)d_in[14];

    const int n = in_sizes[0] / 128;      // 50000
    const int E = in_sizes[2] / 2;        // 800000
    const int* src = edge;
    const int* dst = edge + E;

    size_t off = 0;
    auto carve = [&](size_t bytes) {
        size_t p = off;
        off = (off + bytes + 255) & ~(size_t)255;
        return p;
    };
    char* ws = (char*)d_ws;
    int*   cnt     = (int*)(ws + carve((size_t)n * 4));
    int*   rowptr  = (int*)(ws + carve((size_t)(n + 1) * 4));
    int*   cursor  = (int*)(ws + carve((size_t)n * 4));
    int*   partial = (int*)(ws + carve(1024));
    int*   csr     = (int*)(ws + carve((size_t)E * 4));
    float* ew      = (float*)(ws + carve((size_t)E * 4));
    float* dis     = (float*)(ws + carve((size_t)n * 4));
    float* bufA    = (float*)(ws + carve((size_t)n * 128 * 4));
    float* bufB    = (float*)(ws + carve((size_t)n * 128 * 4));
    float* bufC    = (float*)(ws + carve((size_t)n * 64 * 4));
    (void)ws_size; (void)n_in; (void)out_size;

    float* x_emb = (float*)d_out;             // [n,64]
    float* y_emb = (float*)d_out + (size_t)n * 64;

    const int nb = (n + 255) / 256;  // 196 scan blocks

    hipMemsetAsync(cnt, 0, (size_t)n * 4, stream);
    k_count<<<(E + 255) / 256, 256, 0, stream>>>(dst, E, cnt);
    k_dis<<<(n + 255) / 256, 256, 0, stream>>>(cnt, dis, n);
    k_blocksum<<<nb, 256, 0, stream>>>(cnt, n, partial);
    k_scanpartial<<<1, 256, 0, stream>>>(partial, nb, rowptr, n);
    k_scatterptr<<<nb, 256, 0, stream>>>(cnt, partial, n, rowptr, cursor);
    k_fill<<<(E + 255) / 256, 256, 0, stream>>>(src, dst, E, cursor, dis, csr, ew);

    const int gemm_grid = (n + 31) / 32;
    const int agg_grid = (n + 3) / 4;

    gemm_xw<128><<<gemm_grid, 256, 0, stream>>>(x, W1, bufA, n);
    agg<128, true, false><<<agg_grid, 256, 0, stream>>>(bufA, dis, rowptr, csr, ew, b1, bufB, n);
    gemm_xw<128><<<gemm_grid, 256, 0, stream>>>(bufB, W2, bufA, n);
    agg<128, true, false><<<agg_grid, 256, 0, stream>>>(bufA, dis, rowptr, csr, ew, b2, bufB, n);
    gemm_xw<64><<<gemm_grid, 256, 0, stream>>>(bufB, W3, bufC, n);
    agg<64, false, true><<<agg_grid, 256, 0, stream>>>(bufC, dis, rowptr, csr, ew, b3, x_emb, n);

    target_mlp<<<256, 256, 0, stream>>>(y, bng, bnb, Wm1, bm1, Wm2, bm2, y_emb);
}

// Round 3
// 338.019 us; speedup vs baseline: 1.4336x; 1.2656x over previous
//
#include <hip/hip_runtime.h>
#include <hip/hip_bf16.h>

typedef __attribute__((ext_vector_type(8))) short short8;
typedef __attribute__((ext_vector_type(4))) float f32x4;

__device__ __forceinline__ ushort f2bf(float f) {
    union { float f; uint u; } v; v.f = f;
    uint u = v.u;
    return (ushort)((u + 0x7fffu + ((u >> 16) & 1u)) >> 16);  // RNE
}
__device__ __forceinline__ float bf_lo(uint u) { return __uint_as_float(u << 16); }
__device__ __forceinline__ float bf_hi(uint u) { return __uint_as_float(u & 0xffff0000u); }
__device__ __forceinline__ float lane_bcast_f(float v, int j) {
    return __uint_as_float(__builtin_amdgcn_readlane(__float_as_uint(v), j));
}

// ---------------------------------------------------------------------------
// CSR build kernels
// ---------------------------------------------------------------------------
__global__ void k_count(const int* __restrict__ dst, int E, int* __restrict__ cnt) {
    int i = blockIdx.x * blockDim.x + threadIdx.x;
    if (i < E) atomicAdd(&cnt[dst[i]], 1);
}

__global__ void k_dis(const int* __restrict__ cnt, float* __restrict__ dis, int n) {
    int i = blockIdx.x * blockDim.x + threadIdx.x;
    if (i < n) dis[i] = rsqrtf((float)(cnt[i] + 1));  // +1 self loop
}

__global__ void k_blocksum(const int* __restrict__ cnt, int n, int* __restrict__ partial) {
    __shared__ int sm[256];
    int tid = threadIdx.x;
    int i = blockIdx.x * 256 + tid;
    sm[tid] = (i < n) ? cnt[i] : 0;
    __syncthreads();
    for (int s = 128; s > 0; s >>= 1) {
        if (tid < s) sm[tid] += sm[tid + s];
        __syncthreads();
    }
    if (tid == 0) partial[blockIdx.x] = sm[0];
}

__global__ void k_scanpartial(int* __restrict__ partial, int nb, int* __restrict__ rowptr, int n) {
    __shared__ int sm[256];
    int tid = threadIdx.x;
    int mine = (tid < nb) ? partial[tid] : 0;
    sm[tid] = mine;
    __syncthreads();
    for (int off = 1; off < 256; off <<= 1) {
        int v = (tid >= off) ? sm[tid - off] : 0;
        __syncthreads();
        sm[tid] += v;
        __syncthreads();
    }
    if (tid < nb) partial[tid] = sm[tid] - mine;
    if (tid == nb - 1) rowptr[n] = sm[tid];
}

__global__ void k_scatterptr(const int* __restrict__ cnt, const int* __restrict__ partial,
                             int n, int* __restrict__ rowptr, int* __restrict__ cursor) {
    __shared__ int sm[256];
    int tid = threadIdx.x;
    int i = blockIdx.x * 256 + tid;
    int mine = (i < n) ? cnt[i] : 0;
    sm[tid] = mine;
    __syncthreads();
    for (int off = 1; off < 256; off <<= 1) {
        int v = (tid >= off) ? sm[tid - off] : 0;
        __syncthreads();
        sm[tid] += v;
        __syncthreads();
    }
    if (i < n) {
        int p = partial[blockIdx.x] + sm[tid] - mine;
        rowptr[i] = p;
        cursor[i] = p;
    }
}

__global__ void k_fill(const int* __restrict__ src, const int* __restrict__ dst, int E,
                       int* __restrict__ cursor, const float* __restrict__ dis,
                       int* __restrict__ csr, float* __restrict__ ew) {
    int i = blockIdx.x * blockDim.x + threadIdx.x;
    if (i < E) {
        int d = dst[i];
        int s = src[i];
        int p = atomicAdd(&cursor[d], 1);
        csr[p] = s;
        ew[p] = dis[s];
    }
}

// ---------------------------------------------------------------------------
// casts
// ---------------------------------------------------------------------------
__global__ void k_xcast(const float* __restrict__ X, ushort* __restrict__ Xb, int n4) {
    int i = blockIdx.x * 256 + threadIdx.x;
    if (i < n4) {
        float4 v = ((const float4*)X)[i];
        ushort4 o;
        o.x = f2bf(v.x); o.y = f2bf(v.y); o.z = f2bf(v.z); o.w = f2bf(v.w);
        ((ushort4*)Xb)[i] = o;
    }
}

// W[K=128][N] fp32 -> Wt[N][128] bf16
__global__ void k_wcast(const float* __restrict__ W, ushort* __restrict__ Wt, int N) {
    int i = blockIdx.x * 256 + threadIdx.x;
    if (i < 128 * N) {
        int k = i / N, nn = i - k * N;
        Wt[nn * 128 + k] = f2bf(W[i]);
    }
}

// ---------------------------------------------------------------------------
// bf16 MFMA GEMM: Y[n,COLS](bf16) = Xb[n,128](bf16) @ W(bf16, pre-transposed Wt[COLS][128])
// block = 256 thr (4 waves); tile M=64 x N=COLS; K=128 fully LDS-resident.
// wave w covers cols [w*COLS/4, ...); per wave: 4 M-tiles x NT N-tiles of 16x16x32.
// ---------------------------------------------------------------------------
template <int COLS>
__global__ __launch_bounds__(256) void gemm_mfma(const ushort* __restrict__ Xb,
                                                 const ushort* __restrict__ Wt,
                                                 ushort* __restrict__ Y, int n) {
    constexpr int LDW = 136;  // +8 pad: ds_read_b128 2-way conflict (free)
    __shared__ ushort sX[64 * LDW];
    __shared__ ushort sW[COLS * LDW];
    const int tid = threadIdx.x;
    const int row0 = blockIdx.x * 64;

    // stage X tile (row-clamped) and Wt, 16B chunks
#pragma unroll
    for (int c = tid; c < 64 * 16; c += 256) {
        int r = c >> 4, kc = c & 15;
        int gr = min(row0 + r, n - 1);
        uint4 v = *(const uint4*)&Xb[(size_t)gr * 128 + kc * 8];
        *(uint4*)&sX[r * LDW + kc * 8] = v;
    }
#pragma unroll
    for (int c = tid; c < COLS * 16; c += 256) {
        int r = c >> 4, kc = c & 15;
        uint4 v = *(const uint4*)&Wt[(size_t)r * 128 + kc * 8];
        *(uint4*)&sW[r * LDW + kc * 8] = v;
    }
    __syncthreads();

    constexpr int NT = (COLS == 128) ? 2 : 1;
    constexpr int WN = COLS / 4;  // 32 or 16
    const int w = tid >> 6;
    const int lane = tid & 63;
    const int lm = lane & 15;
    const int kq = lane >> 4;  // 0..3

    f32x4 acc[4][NT];
#pragma unroll
    for (int mt = 0; mt < 4; ++mt)
#pragma unroll
        for (int ntn = 0; ntn < NT; ++ntn) acc[mt][ntn] = (f32x4){0.f, 0.f, 0.f, 0.f};

#pragma unroll
    for (int ks = 0; ks < 4; ++ks) {
        const int k0 = ks * 32 + kq * 8;
        short8 bfr[NT];
#pragma unroll
        for (int ntn = 0; ntn < NT; ++ntn)
            bfr[ntn] = *(const short8*)&sW[(w * WN + ntn * 16 + lm) * LDW + k0];
#pragma unroll
        for (int mt = 0; mt < 4; ++mt) {
            short8 afr = *(const short8*)&sX[(mt * 16 + lm) * LDW + k0];
#pragma unroll
            for (int ntn = 0; ntn < NT; ++ntn)
                acc[mt][ntn] = __builtin_amdgcn_mfma_f32_16x16x32_bf16(afr, bfr[ntn], acc[mt][ntn], 0, 0, 0);
        }
    }

    // epilogue: D[row=(lane>>4)*4+rr][col=lane&15] per 16x16 tile
#pragma unroll
    for (int mt = 0; mt < 4; ++mt) {
        int r_base = row0 + mt * 16 + kq * 4;
#pragma unroll
        for (int ntn = 0; ntn < NT; ++ntn) {
            int col = w * WN + ntn * 16 + lm;
#pragma unroll
            for (int rr = 0; rr < 4; ++rr) {
                int r = r_base + rr;
                if (r < n) Y[(size_t)r * COLS + col] = f2bf(acc[mt][ntn][rr]);
            }
        }
    }
}

// ---------------------------------------------------------------------------
// Aggregation over bf16 H: out[v] = act( dv*(sum_e ew[e]*H[csr[e]] + dv*H[v]) + b )
// One wave/node; lane-parallel (csr,ew) staging + readlane broadcast;
// 8 independent row gathers in flight. COLS=128: uint(bf16x2)/lane.
// ---------------------------------------------------------------------------
template <int COLS, bool RELU, bool NORM>
__global__ __launch_bounds__(256) void agg(const ushort* __restrict__ H,
                                           const float* __restrict__ dis,
                                           const int* __restrict__ rowptr,
                                           const int* __restrict__ csr,
                                           const float* __restrict__ ew,
                                           const float* __restrict__ bias,
                                           void* __restrict__ out, int n) {
    const int wid = blockIdx.x * 4 + (threadIdx.x >> 6);
    const int lane = threadIdx.x & 63;
    if (wid >= n) return;
    const int v = wid;
    const float dv = dis[v];
    const int e0 = rowptr[v];
    const int e1 = rowptr[v + 1];

    if (COLS == 128) {
        const uint* Hu = (const uint*)H;
        uint h0 = Hu[(size_t)v * 64 + lane];
        float ax = dv * bf_lo(h0), ay = dv * bf_hi(h0);

        int e = e0;
        while (e < e1) {
            const int c = min(e1 - e, 64);
            int sidx = 0; float sw = 0.0f;
            if (lane < c) { sidx = csr[e + lane]; sw = ew[e + lane]; }
            int j = 0;
            for (; j + 8 <= c; j += 8) {
                uint hv[8]; float w[8];
#pragma unroll
                for (int u = 0; u < 8; ++u) {
                    int s = __builtin_amdgcn_readlane(sidx, j + u);
                    w[u] = lane_bcast_f(sw, j + u);
                    hv[u] = Hu[(size_t)s * 64 + lane];
                }
#pragma unroll
                for (int u = 0; u < 8; ++u) { ax += w[u] * bf_lo(hv[u]); ay += w[u] * bf_hi(hv[u]); }
            }
            for (; j + 4 <= c; j += 4) {
                uint hv[4]; float w[4];
#pragma unroll
                for (int u = 0; u < 4; ++u) {
                    int s = __builtin_amdgcn_readlane(sidx, j + u);
                    w[u] = lane_bcast_f(sw, j + u);
                    hv[u] = Hu[(size_t)s * 64 + lane];
                }
#pragma unroll
                for (int u = 0; u < 4; ++u) { ax += w[u] * bf_lo(hv[u]); ay += w[u] * bf_hi(hv[u]); }
            }
            for (; j < c; ++j) {
                int s = __builtin_amdgcn_readlane(sidx, j);
                float w = lane_bcast_f(sw, j);
                uint hh = Hu[(size_t)s * 64 + lane];
                ax += w * bf_lo(hh); ay += w * bf_hi(hh);
            }
            e += c;
        }

        float2 b = ((const float2*)bias)[lane];
        float rx = dv * ax + b.x;
        float ry = dv * ay + b.y;
        if (RELU) { rx = fmaxf(rx, 0.f); ry = fmaxf(ry, 0.f); }
        uint packed = (uint)f2bf(rx) | ((uint)f2bf(ry) << 16);
        ((uint*)out)[(size_t)v * 64 + lane] = packed;
    } else {
        float acc = dv * bf_lo((uint)H[(size_t)v * 64 + lane]);

        int e = e0;
        while (e < e1) {
            const int c = min(e1 - e, 64);
            int sidx = 0; float sw = 0.0f;
            if (lane < c) { sidx = csr[e + lane]; sw = ew[e + lane]; }
            int j = 0;
            for (; j + 8 <= c; j += 8) {
                ushort hv[8]; float w[8];
#pragma unroll
                for (int u = 0; u < 8; ++u) {
                    int s = __builtin_amdgcn_readlane(sidx, j + u);
                    w[u] = lane_bcast_f(sw, j + u);
                    hv[u] = H[(size_t)s * 64 + lane];
                }
#pragma unroll
                for (int u = 0; u < 8; ++u) acc += w[u] * bf_lo((uint)hv[u]);
            }
            for (; j < c; ++j) {
                int s = __builtin_amdgcn_readlane(sidx, j);
                float w = lane_bcast_f(sw, j);
                acc += w * bf_lo((uint)H[(size_t)s * 64 + lane]);
            }
            e += c;
        }

        float r = dv * acc + bias[lane];
        if (RELU) r = fmaxf(r, 0.f);
        if (NORM) {
            float ss = r * r;
#pragma unroll
            for (int m = 1; m < 64; m <<= 1) ss += __shfl_xor(ss, m, 64);
            r = r / fmaxf(sqrtf(ss), 1e-12f);
        }
        ((float*)out)[(size_t)v * 64 + lane] = r;
    }
}

// ---------------------------------------------------------------------------
// Target branch: BN(y) -> Linear(1,128) -> ReLU -> Linear(128,64) -> row norm
// ---------------------------------------------------------------------------
__global__ __launch_bounds__(256) void target_mlp(const float* __restrict__ y,
                                                  const float* __restrict__ gamma,
                                                  const float* __restrict__ beta,
                                                  const float* __restrict__ Wm1,
                                                  const float* __restrict__ bm1,
                                                  const float* __restrict__ Wm2,
                                                  const float* __restrict__ bm2,
                                                  float* __restrict__ out) {
    __shared__ float red[256];
    __shared__ float t1[128];
    __shared__ float s_mu, s_var;
    const int tid = threadIdx.x;
    float yv = y[tid];
    red[tid] = yv;
    __syncthreads();
    for (int s = 128; s > 0; s >>= 1) {
        if (tid < s) red[tid] += red[tid + s];
        __syncthreads();
    }
    if (tid == 0) s_mu = red[0] * (1.0f / 256.0f);
    __syncthreads();
    float mu = s_mu;
    float d = yv - mu;
    red[tid] = d * d;
    __syncthreads();
    for (int s = 128; s > 0; s >>= 1) {
        if (tid < s) red[tid] += red[tid + s];
        __syncthreads();
    }
    if (tid == 0) s_var = red[0] * (1.0f / 256.0f);
    __syncthreads();

    const int row = blockIdx.x;
    float yb = (y[row] - mu) * rsqrtf(s_var + 1e-5f) * gamma[0] + beta[0];
    if (tid < 128) t1[tid] = fmaxf(yb * Wm1[tid] + bm1[tid], 0.0f);
    __syncthreads();
    if (tid < 64) {
        float acc = bm2[tid];
#pragma unroll 8
        for (int c = 0; c < 128; ++c) acc += t1[c] * Wm2[c * 64 + tid];
        float ss = acc * acc;
#pragma unroll
        for (int m = 1; m < 64; m <<= 1) ss += __shfl_xor(ss, m, 64);
        out[row * 64 + tid] = acc / fmaxf(sqrtf(ss), 1e-12f);
    }
}

// ---------------------------------------------------------------------------
extern "C" void kernel_launch(void* const* d_in, const int* in_sizes, int n_in,
                              void* d_out, int out_size, void* d_ws, size_t ws_size,
                              hipStream_t stream) {
    const float* x     = (const float*)d_in[0];
    const float* y     = (const float*)d_in[1];
    const int*   edge  = (const int*)d_in[2];
    const float* W1    = (const float*)d_in[3];
    const float* b1    = (const float*)d_in[4];
    const float* W2    = (const float*)d_in[5];
    const float* b2    = (const float*)d_in[6];
    const float* W3    = (const float*)d_in[7];
    const float* b3    = (const float*)d_in[8];
    const float* bng   = (const float*)d_in[9];
    const float* bnb   = (const float*)d_in[10];
    const float* Wm1   = (const float*)d_in[11];
    const float* bm1   = (const float*)d_in[12];
    const float* Wm2   = (const float*)d_in[13];
    const float* bm2   = (const float*)d_in[14];

    const int n = in_sizes[0] / 128;  // 50000
    const int E = in_sizes[2] / 2;    // 800000
    const int* src = edge;
    const int* dst = edge + E;

    size_t off = 0;
    auto carve = [&](size_t bytes) {
        size_t p = off;
        off = (off + bytes + 255) & ~(size_t)255;
        return p;
    };
    char* ws = (char*)d_ws;
    int*    cnt     = (int*)(ws + carve((size_t)n * 4));
    int*    rowptr  = (int*)(ws + carve((size_t)(n + 1) * 4));
    int*    cursor  = (int*)(ws + carve((size_t)n * 4));
    int*    partial = (int*)(ws + carve(1024));
    int*    csr     = (int*)(ws + carve((size_t)E * 4));
    float*  ew      = (float*)(ws + carve((size_t)E * 4));
    float*  dis     = (float*)(ws + carve((size_t)n * 4));
    ushort* xb      = (ushort*)(ws + carve((size_t)n * 128 * 2));
    ushort* wt1     = (ushort*)(ws + carve(128 * 128 * 2));
    ushort* wt2     = (ushort*)(ws + carve(128 * 128 * 2));
    ushort* wt3     = (ushort*)(ws + carve(64 * 128 * 2));
    ushort* bufA    = (ushort*)(ws + carve((size_t)n * 128 * 2));
    ushort* bufB    = (ushort*)(ws + carve((size_t)n * 128 * 2));
    ushort* bufC    = (ushort*)(ws + carve((size_t)n * 64 * 2));
    (void)ws_size; (void)n_in; (void)out_size;

    float* x_emb = (float*)d_out;
    float* y_emb = (float*)d_out + (size_t)n * 64;

    const int nb = (n + 255) / 256;

    hipMemsetAsync(cnt, 0, (size_t)n * 4, stream);
    k_count<<<(E + 255) / 256, 256, 0, stream>>>(dst, E, cnt);
    k_dis<<<(n + 255) / 256, 256, 0, stream>>>(cnt, dis, n);
    k_blocksum<<<nb, 256, 0, stream>>>(cnt, n, partial);
    k_scanpartial<<<1, 256, 0, stream>>>(partial, nb, rowptr, n);
    k_scatterptr<<<nb, 256, 0, stream>>>(cnt, partial, n, rowptr, cursor);
    k_fill<<<(E + 255) / 256, 256, 0, stream>>>(src, dst, E, cursor, dis, csr, ew);

    k_xcast<<<((n * 128 / 4) + 255) / 256, 256, 0, stream>>>(x, xb, n * 128 / 4);
    k_wcast<<<(128 * 128 + 255) / 256, 256, 0, stream>>>(W1, wt1, 128);
    k_wcast<<<(128 * 128 + 255) / 256, 256, 0, stream>>>(W2, wt2, 128);
    k_wcast<<<(128 * 64 + 255) / 256, 256, 0, stream>>>(W3, wt3, 64);

    const int ggrid = (n + 63) / 64;  // 782
    const int agrid = (n + 3) / 4;

    gemm_mfma<128><<<ggrid, 256, 0, stream>>>(xb, wt1, bufA, n);
    agg<128, true, false><<<agrid, 256, 0, stream>>>(bufA, dis, rowptr, csr, ew, b1, bufB, n);
    gemm_mfma<128><<<ggrid, 256, 0, stream>>>(bufB, wt2, bufA, n);
    agg<128, true, false><<<agrid, 256, 0, stream>>>(bufA, dis, rowptr, csr, ew, b2, bufB, n);
    gemm_mfma<64><<<ggrid, 256, 0, stream>>>(bufB, wt3, bufC, n);
    agg<64, false, true><<<agrid, 256, 0, stream>>>(bufC, dis, rowptr, csr, ew, b3, x_emb, n);

    target_mlp<<<256, 256, 0, stream>>>(y, bng, bnb, Wm1, bm1, Wm2, bm2, y_emb);
}

// Round 4
// 280.349 us; speedup vs baseline: 1.7285x; 1.2057x over previous
//
#include <hip/hip_runtime.h>
#include <hip/hip_bf16.h>

typedef __attribute__((ext_vector_type(8))) short short8;
typedef __attribute__((ext_vector_type(4))) float f32x4;

__device__ __forceinline__ ushort f2bf(float f) {
    union { float f; uint u; } v; v.f = f;
    uint u = v.u;
    return (ushort)((u + 0x7fffu + ((u >> 16) & 1u)) >> 16);  // RNE
}
__device__ __forceinline__ float bf_lo(uint u) { return __uint_as_float(u << 16); }
__device__ __forceinline__ float bf_hi(uint u) { return __uint_as_float(u & 0xffff0000u); }
__device__ __forceinline__ float lane_bcast_f(float v, int j) {
    return __uint_as_float(__builtin_amdgcn_readlane(__float_as_uint(v), j));
}

// ---------------------------------------------------------------------------
// CSR build: coarse partition by dst>>8, then per-bucket counting sort.
// Edges packed as (dst<<16)|src (both < 65536).
// ---------------------------------------------------------------------------
#define PCHUNK 4096

__global__ __launch_bounds__(256) void k_partition(const int* __restrict__ src,
                                                   const int* __restrict__ dst, int E,
                                                   int nbuck, int cap,
                                                   int* __restrict__ gcur,
                                                   uint* __restrict__ part) {
    __shared__ int hist[256];
    __shared__ int base[256];
    __shared__ int cnt2[256];
    const int tid = threadIdx.x;
    const int s0 = blockIdx.x * PCHUNK;
    const int send = min(s0 + PCHUNK, E);
    hist[tid] = 0;
    cnt2[tid] = 0;
    __syncthreads();
    for (int i = s0 + tid; i < send; i += 256) {
        int d = dst[i];
        atomicAdd(&hist[d >> 8], 1);
    }
    __syncthreads();
    if (tid < nbuck && hist[tid] > 0) base[tid] = atomicAdd(&gcur[tid], hist[tid]);
    __syncthreads();
    for (int i = s0 + tid; i < send; i += 256) {
        int d = dst[i];
        int s = src[i];
        int k = d >> 8;
        int r = base[k] + atomicAdd(&cnt2[k], 1);
        if (r < cap) part[(size_t)k * cap + r] = ((uint)d << 16) | (uint)s;
    }
}

// exclusive scan of gcur[nbuck] -> bstart[0..nbuck]
__global__ void k_bucketscan(const int* __restrict__ gcur, int nbuck, int* __restrict__ bstart) {
    __shared__ int sm[256];
    int tid = threadIdx.x;
    int v = (tid < nbuck) ? gcur[tid] : 0;
    sm[tid] = v;
    __syncthreads();
    for (int off = 1; off < 256; off <<= 1) {
        int t = (tid >= off) ? sm[tid - off] : 0;
        __syncthreads();
        sm[tid] += t;
        __syncthreads();
    }
    if (tid < nbuck) bstart[tid] = sm[tid] - v;
    if (tid == nbuck - 1) bstart[nbuck] = sm[tid];
}

// one block per bucket: counting sort over the bucket's 256-node dst range.
// Produces rowptr, dis (rsqrt(deg+1)), and csr (src per edge, grouped by dst).
__global__ __launch_bounds__(256) void k_bucket_sort(const uint* __restrict__ part,
                                                     const int* __restrict__ gcur,
                                                     const int* __restrict__ bstart,
                                                     int cap, int n,
                                                     int* __restrict__ rowptr,
                                                     float* __restrict__ dis,
                                                     int* __restrict__ csr) {
    __shared__ int hist[256];
    __shared__ int pfx[256];
    const int b = blockIdx.x;
    const int tid = threadIdx.x;
    int sz = gcur[b];
    if (sz > cap) sz = cap;
    const uint* seg = part + (size_t)b * cap;
    const int outbase = bstart[b];

    hist[tid] = 0;
    __syncthreads();
    for (int i = tid; i < sz; i += 256) atomicAdd(&hist[(seg[i] >> 16) & 255], 1);
    __syncthreads();

    int cnt_t = hist[tid];
    pfx[tid] = cnt_t;
    __syncthreads();
    for (int off = 1; off < 256; off <<= 1) {
        int t = (tid >= off) ? pfx[tid - off] : 0;
        __syncthreads();
        pfx[tid] += t;
        __syncthreads();
    }
    int excl = pfx[tid] - cnt_t;

    int node = b * 256 + tid;
    if (node < n) {
        rowptr[node] = outbase + excl;
        dis[node] = rsqrtf((float)(cnt_t + 1));  // +1 self loop
        if (node == n - 1) rowptr[n] = outbase + excl + cnt_t;
    }
    __syncthreads();
    pfx[tid] = excl;   // now exclusive prefix
    hist[tid] = 0;     // running counters
    __syncthreads();
    for (int i = tid; i < sz; i += 256) {
        uint p = seg[i];
        int j = (p >> 16) & 255;
        int r = atomicAdd(&hist[j], 1);
        csr[outbase + pfx[j] + r] = (int)(p & 0xffffu);
    }
}

__global__ void k_ew(const int* __restrict__ csr, const float* __restrict__ dis,
                     float* __restrict__ ew, int E) {
    int i = blockIdx.x * 256 + threadIdx.x;
    if (i < E) ew[i] = dis[csr[i]];
}

// ---------------------------------------------------------------------------
// casts
// ---------------------------------------------------------------------------
__global__ void k_xcast(const float* __restrict__ X, ushort* __restrict__ Xb, int n4) {
    int i = blockIdx.x * 256 + threadIdx.x;
    if (i < n4) {
        float4 v = ((const float4*)X)[i];
        ushort4 o;
        o.x = f2bf(v.x); o.y = f2bf(v.y); o.z = f2bf(v.z); o.w = f2bf(v.w);
        ((ushort4*)Xb)[i] = o;
    }
}

// W[K=128][N] fp32 -> Wt[N][128] bf16
__global__ void k_wcast(const float* __restrict__ W, ushort* __restrict__ Wt, int N) {
    int i = blockIdx.x * 256 + threadIdx.x;
    if (i < 128 * N) {
        int k = i / N, nn = i - k * N;
        Wt[nn * 128 + k] = f2bf(W[i]);
    }
}

// ---------------------------------------------------------------------------
// bf16 MFMA GEMM: Y[n,COLS](bf16) = Xb[n,128](bf16) @ Wt[COLS][128](bf16)
// ---------------------------------------------------------------------------
template <int COLS>
__global__ __launch_bounds__(256) void gemm_mfma(const ushort* __restrict__ Xb,
                                                 const ushort* __restrict__ Wt,
                                                 ushort* __restrict__ Y, int n) {
    constexpr int LDW = 136;  // +8 pad
    __shared__ ushort sX[64 * LDW];
    __shared__ ushort sW[COLS * LDW];
    const int tid = threadIdx.x;
    const int row0 = blockIdx.x * 64;

#pragma unroll
    for (int c = tid; c < 64 * 16; c += 256) {
        int r = c >> 4, kc = c & 15;
        int gr = min(row0 + r, n - 1);
        uint4 v = *(const uint4*)&Xb[(size_t)gr * 128 + kc * 8];
        *(uint4*)&sX[r * LDW + kc * 8] = v;
    }
#pragma unroll
    for (int c = tid; c < COLS * 16; c += 256) {
        int r = c >> 4, kc = c & 15;
        uint4 v = *(const uint4*)&Wt[(size_t)r * 128 + kc * 8];
        *(uint4*)&sW[r * LDW + kc * 8] = v;
    }
    __syncthreads();

    constexpr int NT = (COLS == 128) ? 2 : 1;
    constexpr int WN = COLS / 4;
    const int w = tid >> 6;
    const int lane = tid & 63;
    const int lm = lane & 15;
    const int kq = lane >> 4;

    f32x4 acc[4][NT];
#pragma unroll
    for (int mt = 0; mt < 4; ++mt)
#pragma unroll
        for (int ntn = 0; ntn < NT; ++ntn) acc[mt][ntn] = (f32x4){0.f, 0.f, 0.f, 0.f};

#pragma unroll
    for (int ks = 0; ks < 4; ++ks) {
        const int k0 = ks * 32 + kq * 8;
        short8 bfr[NT];
#pragma unroll
        for (int ntn = 0; ntn < NT; ++ntn)
            bfr[ntn] = *(const short8*)&sW[(w * WN + ntn * 16 + lm) * LDW + k0];
#pragma unroll
        for (int mt = 0; mt < 4; ++mt) {
            short8 afr = *(const short8*)&sX[(mt * 16 + lm) * LDW + k0];
#pragma unroll
            for (int ntn = 0; ntn < NT; ++ntn)
                acc[mt][ntn] = __builtin_amdgcn_mfma_f32_16x16x32_bf16(afr, bfr[ntn], acc[mt][ntn], 0, 0, 0);
        }
    }

#pragma unroll
    for (int mt = 0; mt < 4; ++mt) {
        int r_base = row0 + mt * 16 + kq * 4;
#pragma unroll
        for (int ntn = 0; ntn < NT; ++ntn) {
            int col = w * WN + ntn * 16 + lm;
#pragma unroll
            for (int rr = 0; rr < 4; ++rr) {
                int r = r_base + rr;
                if (r < n) Y[(size_t)r * COLS + col] = f2bf(acc[mt][ntn][rr]);
            }
        }
    }
}

// ---------------------------------------------------------------------------
// Aggregation over bf16 H (unchanged from round 3)
// ---------------------------------------------------------------------------
template <int COLS, bool RELU, bool NORM>
__global__ __launch_bounds__(256) void agg(const ushort* __restrict__ H,
                                           const float* __restrict__ dis,
                                           const int* __restrict__ rowptr,
                                           const int* __restrict__ csr,
                                           const float* __restrict__ ew,
                                           const float* __restrict__ bias,
                                           void* __restrict__ out, int n) {
    const int wid = blockIdx.x * 4 + (threadIdx.x >> 6);
    const int lane = threadIdx.x & 63;
    if (wid >= n) return;
    const int v = wid;
    const float dv = dis[v];
    const int e0 = rowptr[v];
    const int e1 = rowptr[v + 1];

    if (COLS == 128) {
        const uint* Hu = (const uint*)H;
        uint h0 = Hu[(size_t)v * 64 + lane];
        float ax = dv * bf_lo(h0), ay = dv * bf_hi(h0);

        int e = e0;
        while (e < e1) {
            const int c = min(e1 - e, 64);
            int sidx = 0; float sw = 0.0f;
            if (lane < c) { sidx = csr[e + lane]; sw = ew[e + lane]; }
            int j = 0;
            for (; j + 8 <= c; j += 8) {
                uint hv[8]; float w[8];
#pragma unroll
                for (int u = 0; u < 8; ++u) {
                    int s = __builtin_amdgcn_readlane(sidx, j + u);
                    w[u] = lane_bcast_f(sw, j + u);
                    hv[u] = Hu[(size_t)s * 64 + lane];
                }
#pragma unroll
                for (int u = 0; u < 8; ++u) { ax += w[u] * bf_lo(hv[u]); ay += w[u] * bf_hi(hv[u]); }
            }
            for (; j + 4 <= c; j += 4) {
                uint hv[4]; float w[4];
#pragma unroll
                for (int u = 0; u < 4; ++u) {
                    int s = __builtin_amdgcn_readlane(sidx, j + u);
                    w[u] = lane_bcast_f(sw, j + u);
                    hv[u] = Hu[(size_t)s * 64 + lane];
                }
#pragma unroll
                for (int u = 0; u < 4; ++u) { ax += w[u] * bf_lo(hv[u]); ay += w[u] * bf_hi(hv[u]); }
            }
            for (; j < c; ++j) {
                int s = __builtin_amdgcn_readlane(sidx, j);
                float w = lane_bcast_f(sw, j);
                uint hh = Hu[(size_t)s * 64 + lane];
                ax += w * bf_lo(hh); ay += w * bf_hi(hh);
            }
            e += c;
        }

        float2 b = ((const float2*)bias)[lane];
        float rx = dv * ax + b.x;
        float ry = dv * ay + b.y;
        if (RELU) { rx = fmaxf(rx, 0.f); ry = fmaxf(ry, 0.f); }
        uint packed = (uint)f2bf(rx) | ((uint)f2bf(ry) << 16);
        ((uint*)out)[(size_t)v * 64 + lane] = packed;
    } else {
        float acc = dv * bf_lo((uint)H[(size_t)v * 64 + lane]);

        int e = e0;
        while (e < e1) {
            const int c = min(e1 - e, 64);
            int sidx = 0; float sw = 0.0f;
            if (lane < c) { sidx = csr[e + lane]; sw = ew[e + lane]; }
            int j = 0;
            for (; j + 8 <= c; j += 8) {
                ushort hv[8]; float w[8];
#pragma unroll
                for (int u = 0; u < 8; ++u) {
                    int s = __builtin_amdgcn_readlane(sidx, j + u);
                    w[u] = lane_bcast_f(sw, j + u);
                    hv[u] = H[(size_t)s * 64 + lane];
                }
#pragma unroll
                for (int u = 0; u < 8; ++u) acc += w[u] * bf_lo((uint)hv[u]);
            }
            for (; j < c; ++j) {
                int s = __builtin_amdgcn_readlane(sidx, j);
                float w = lane_bcast_f(sw, j);
                acc += w * bf_lo((uint)H[(size_t)s * 64 + lane]);
            }
            e += c;
        }

        float r = dv * acc + bias[lane];
        if (RELU) r = fmaxf(r, 0.f);
        if (NORM) {
            float ss = r * r;
#pragma unroll
            for (int m = 1; m < 64; m <<= 1) ss += __shfl_xor(ss, m, 64);
            r = r / fmaxf(sqrtf(ss), 1e-12f);
        }
        ((float*)out)[(size_t)v * 64 + lane] = r;
    }
}

// ---------------------------------------------------------------------------
// Target branch
// ---------------------------------------------------------------------------
__global__ __launch_bounds__(256) void target_mlp(const float* __restrict__ y,
                                                  const float* __restrict__ gamma,
                                                  const float* __restrict__ beta,
                                                  const float* __restrict__ Wm1,
                                                  const float* __restrict__ bm1,
                                                  const float* __restrict__ Wm2,
                                                  const float* __restrict__ bm2,
                                                  float* __restrict__ out) {
    __shared__ float red[256];
    __shared__ float t1[128];
    __shared__ float s_mu, s_var;
    const int tid = threadIdx.x;
    float yv = y[tid];
    red[tid] = yv;
    __syncthreads();
    for (int s = 128; s > 0; s >>= 1) {
        if (tid < s) red[tid] += red[tid + s];
        __syncthreads();
    }
    if (tid == 0) s_mu = red[0] * (1.0f / 256.0f);
    __syncthreads();
    float mu = s_mu;
    float d = yv - mu;
    red[tid] = d * d;
    __syncthreads();
    for (int s = 128; s > 0; s >>= 1) {
        if (tid < s) red[tid] += red[tid + s];
        __syncthreads();
    }
    if (tid == 0) s_var = red[0] * (1.0f / 256.0f);
    __syncthreads();

    const int row = blockIdx.x;
    float yb = (y[row] - mu) * rsqrtf(s_var + 1e-5f) * gamma[0] + beta[0];
    if (tid < 128) t1[tid] = fmaxf(yb * Wm1[tid] + bm1[tid], 0.0f);
    __syncthreads();
    if (tid < 64) {
        float acc = bm2[tid];
#pragma unroll 8
        for (int c = 0; c < 128; ++c) acc += t1[c] * Wm2[c * 64 + tid];
        float ss = acc * acc;
#pragma unroll
        for (int m = 1; m < 64; m <<= 1) ss += __shfl_xor(ss, m, 64);
        out[row * 64 + tid] = acc / fmaxf(sqrtf(ss), 1e-12f);
    }
}

// ---------------------------------------------------------------------------
extern "C" void kernel_launch(void* const* d_in, const int* in_sizes, int n_in,
                              void* d_out, int out_size, void* d_ws, size_t ws_size,
                              hipStream_t stream) {
    const float* x     = (const float*)d_in[0];
    const float* y     = (const float*)d_in[1];
    const int*   edge  = (const int*)d_in[2];
    const float* W1    = (const float*)d_in[3];
    const float* b1    = (const float*)d_in[4];
    const float* W2    = (const float*)d_in[5];
    const float* b2    = (const float*)d_in[6];
    const float* W3    = (const float*)d_in[7];
    const float* b3    = (const float*)d_in[8];
    const float* bng   = (const float*)d_in[9];
    const float* bnb   = (const float*)d_in[10];
    const float* Wm1   = (const float*)d_in[11];
    const float* bm1   = (const float*)d_in[12];
    const float* Wm2   = (const float*)d_in[13];
    const float* bm2   = (const float*)d_in[14];

    const int n = in_sizes[0] / 128;  // 50000
    const int E = in_sizes[2] / 2;    // 800000
    const int* src = edge;
    const int* dst = edge + E;

    const int nbuck = (n + 255) / 256;               // 196
    const int cap = E / nbuck + E / nbuck / 4 + 1024;  // mean + 25% + slack

    size_t off = 0;
    auto carve = [&](size_t bytes) {
        size_t p = off;
        off = (off + bytes + 255) & ~(size_t)255;
        return p;
    };
    char* ws = (char*)d_ws;
    int*    gcur    = (int*)(ws + carve(256 * 4));
    int*    bstart  = (int*)(ws + carve(257 * 4));
    uint*   part    = (uint*)(ws + carve((size_t)nbuck * cap * 4));
    int*    rowptr  = (int*)(ws + carve((size_t)(n + 1) * 4));
    int*    csr     = (int*)(ws + carve((size_t)E * 4));
    float*  ew      = (float*)(ws + carve((size_t)E * 4));
    float*  dis     = (float*)(ws + carve((size_t)n * 4));
    ushort* xb      = (ushort*)(ws + carve((size_t)n * 128 * 2));
    ushort* wt1     = (ushort*)(ws + carve(128 * 128 * 2));
    ushort* wt2     = (ushort*)(ws + carve(128 * 128 * 2));
    ushort* wt3     = (ushort*)(ws + carve(64 * 128 * 2));
    ushort* bufA    = (ushort*)(ws + carve((size_t)n * 128 * 2));
    ushort* bufB    = (ushort*)(ws + carve((size_t)n * 128 * 2));
    ushort* bufC    = (ushort*)(ws + carve((size_t)n * 64 * 2));
    (void)ws_size; (void)n_in; (void)out_size;

    float* x_emb = (float*)d_out;
    float* y_emb = (float*)d_out + (size_t)n * 64;

    hipMemsetAsync(gcur, 0, 256 * 4, stream);
    k_partition<<<(E + PCHUNK - 1) / PCHUNK, 256, 0, stream>>>(src, dst, E, nbuck, cap, gcur, part);
    k_bucketscan<<<1, 256, 0, stream>>>(gcur, nbuck, bstart);
    k_bucket_sort<<<nbuck, 256, 0, stream>>>(part, gcur, bstart, cap, n, rowptr, dis, csr);
    k_ew<<<(E + 255) / 256, 256, 0, stream>>>(csr, dis, ew, E);

    k_xcast<<<((n * 128 / 4) + 255) / 256, 256, 0, stream>>>(x, xb, n * 128 / 4);
    k_wcast<<<(128 * 128 + 255) / 256, 256, 0, stream>>>(W1, wt1, 128);
    k_wcast<<<(128 * 128 + 255) / 256, 256, 0, stream>>>(W2, wt2, 128);
    k_wcast<<<(128 * 64 + 255) / 256, 256, 0, stream>>>(W3, wt3, 64);

    const int ggrid = (n + 63) / 64;
    const int agrid = (n + 3) / 4;

    gemm_mfma<128><<<ggrid, 256, 0, stream>>>(xb, wt1, bufA, n);
    agg<128, true, false><<<agrid, 256, 0, stream>>>(bufA, dis, rowptr, csr, ew, b1, bufB, n);
    gemm_mfma<128><<<ggrid, 256, 0, stream>>>(bufB, wt2, bufA, n);
    agg<128, true, false><<<agrid, 256, 0, stream>>>(bufA, dis, rowptr, csr, ew, b2, bufB, n);
    gemm_mfma<64><<<ggrid, 256, 0, stream>>>(bufB, wt3, bufC, n);
    agg<64, false, true><<<agrid, 256, 0, stream>>>(bufC, dis, rowptr, csr, ew, b3, x_emb, n);

    target_mlp<<<256, 256, 0, stream>>>(y, bng, bnb, Wm1, bm1, Wm2, bm2, y_emb);
}

// Round 5
// 268.738 us; speedup vs baseline: 1.8032x; 1.0432x over previous
//
#include <hip/hip_runtime.h>
#include <hip/hip_bf16.h>

typedef __attribute__((ext_vector_type(8))) short short8;
typedef __attribute__((ext_vector_type(4))) float f32x4;

__device__ __forceinline__ ushort f2bf(float f) {
    union { float f; uint u; } v; v.f = f;
    uint u = v.u;
    return (ushort)((u + 0x7fffu + ((u >> 16) & 1u)) >> 16);  // RNE
}
__device__ __forceinline__ float bf_lo(uint u) { return __uint_as_float(u << 16); }
__device__ __forceinline__ float bf_hi(uint u) { return __uint_as_float(u & 0xffff0000u); }
__device__ __forceinline__ float lane_bcast_f(float v, int j) {
    return __uint_as_float(__builtin_amdgcn_readlane(__float_as_uint(v), j));
}

// ---------------------------------------------------------------------------
// CSR build: coarse partition by dst>>8, then per-bucket counting sort
// (with inline bucket-offset scan). Edges packed as (dst<<16)|src.
// ---------------------------------------------------------------------------
#define PCHUNK 4096

__global__ __launch_bounds__(256) void k_partition(const int* __restrict__ src,
                                                   const int* __restrict__ dst, int E,
                                                   int nbuck, int cap,
                                                   int* __restrict__ gcur,
                                                   uint* __restrict__ part) {
    __shared__ int hist[256];
    __shared__ int base[256];
    __shared__ int cnt2[256];
    const int tid = threadIdx.x;
    const int s0 = blockIdx.x * PCHUNK;
    const int send = min(s0 + PCHUNK, E);
    hist[tid] = 0;
    cnt2[tid] = 0;
    __syncthreads();
    for (int i = s0 + tid; i < send; i += 256) {
        int d = dst[i];
        atomicAdd(&hist[d >> 8], 1);
    }
    __syncthreads();
    if (tid < nbuck && hist[tid] > 0) base[tid] = atomicAdd(&gcur[tid], hist[tid]);
    __syncthreads();
    for (int i = s0 + tid; i < send; i += 256) {
        int d = dst[i];
        int s = src[i];
        int k = d >> 8;
        int r = base[k] + atomicAdd(&cnt2[k], 1);
        if (r < cap) part[(size_t)k * cap + r] = ((uint)d << 16) | (uint)s;
    }
}

// one block per bucket: inline scan of gcur for the output base, then
// counting sort over the bucket's 256-node dst range.
// Produces rowptr, dis (rsqrt(deg+1)), csr (src per edge, grouped by dst).
__global__ __launch_bounds__(256) void k_bucket_sort(const uint* __restrict__ part,
                                                     const int* __restrict__ gcur,
                                                     int nbuck, int cap, int n,
                                                     int* __restrict__ rowptr,
                                                     float* __restrict__ dis,
                                                     int* __restrict__ csr) {
    __shared__ int hist[256];
    __shared__ int pfx[256];
    __shared__ int sscan[256];
    const int b = blockIdx.x;
    const int tid = threadIdx.x;

    // inline exclusive scan of min(gcur,cap) to get this bucket's out base
    int gv = (tid < nbuck) ? min(gcur[tid], cap) : 0;
    sscan[tid] = gv;
    __syncthreads();
    for (int off = 1; off < 256; off <<= 1) {
        int t = (tid >= off) ? sscan[tid - off] : 0;
        __syncthreads();
        sscan[tid] += t;
        __syncthreads();
    }
    const int outbase = (b == 0) ? 0 : sscan[b - 1];
    const int sz = min(gcur[b], cap);
    const uint* seg = part + (size_t)b * cap;

    hist[tid] = 0;
    __syncthreads();
    for (int i = tid; i < sz; i += 256) atomicAdd(&hist[(seg[i] >> 16) & 255], 1);
    __syncthreads();

    int cnt_t = hist[tid];
    pfx[tid] = cnt_t;
    __syncthreads();
    for (int off = 1; off < 256; off <<= 1) {
        int t = (tid >= off) ? pfx[tid - off] : 0;
        __syncthreads();
        pfx[tid] += t;
        __syncthreads();
    }
    int excl = pfx[tid] - cnt_t;

    int node = b * 256 + tid;
    if (node < n) {
        rowptr[node] = outbase + excl;
        dis[node] = rsqrtf((float)(cnt_t + 1));  // +1 self loop
        if (node == n - 1) rowptr[n] = outbase + excl + cnt_t;
    }
    __syncthreads();
    pfx[tid] = excl;
    hist[tid] = 0;
    __syncthreads();
    for (int i = tid; i < sz; i += 256) {
        uint p = seg[i];
        int j = (p >> 16) & 255;
        int r = atomicAdd(&hist[j], 1);
        csr[outbase + pfx[j] + r] = (int)(p & 0xffffu);
    }
}

// ---------------------------------------------------------------------------
// fused weight cast: W[128][N] fp32 -> Wt[N][128] bf16, for W1,W2,W3
// ---------------------------------------------------------------------------
__global__ void k_wcast3(const float* __restrict__ W1, const float* __restrict__ W2,
                         const float* __restrict__ W3,
                         ushort* __restrict__ wt1, ushort* __restrict__ wt2,
                         ushort* __restrict__ wt3) {
    int i = blockIdx.x * 256 + threadIdx.x;
    // segments: [0,16384) W1 (N=128), [16384,32768) W2 (N=128), [32768,40960) W3 (N=64)
    if (i < 16384) {
        int k = i >> 7, nn = i & 127;
        wt1[nn * 128 + k] = f2bf(W1[i]);
    } else if (i < 32768) {
        int j = i - 16384;
        int k = j >> 7, nn = j & 127;
        wt2[nn * 128 + k] = f2bf(W2[j]);
    } else if (i < 40960) {
        int j = i - 32768;
        int k = j >> 6, nn = j & 63;
        wt3[nn * 128 + k] = f2bf(W3[j]);
    }
}

// ---------------------------------------------------------------------------
// bf16 MFMA GEMM: Y[n,COLS](bf16) = X[n,128] @ Wt[COLS][128](bf16)
// F32IN: X is fp32, cast during LDS staging (layer 1). Else X is bf16.
// ---------------------------------------------------------------------------
template <int COLS, bool F32IN>
__global__ __launch_bounds__(256) void gemm_mfma(const void* __restrict__ Xin,
                                                 const ushort* __restrict__ Wt,
                                                 ushort* __restrict__ Y, int n) {
    constexpr int LDW = 136;  // +8 pad
    __shared__ ushort sX[64 * LDW];
    __shared__ ushort sW[COLS * LDW];
    const int tid = threadIdx.x;
    const int row0 = blockIdx.x * 64;

    if (F32IN) {
        const float* Xf = (const float*)Xin;
#pragma unroll
        for (int i = 0; i < 8; ++i) {
            int idx = i * 256 + tid;       // 0..2047
            int r = idx >> 5, kc = idx & 31;
            int gr = min(row0 + r, n - 1);
            float4 v = *(const float4*)&Xf[(size_t)gr * 128 + kc * 4];
            ushort4 o;
            o.x = f2bf(v.x); o.y = f2bf(v.y); o.z = f2bf(v.z); o.w = f2bf(v.w);
            *(ushort4*)&sX[r * LDW + kc * 4] = o;
        }
    } else {
        const ushort* Xb = (const ushort*)Xin;
#pragma unroll
        for (int i = 0; i < 4; ++i) {
            int idx = i * 256 + tid;       // 0..1023
            int r = idx >> 4, kc = idx & 15;
            int gr = min(row0 + r, n - 1);
            uint4 v = *(const uint4*)&Xb[(size_t)gr * 128 + kc * 8];
            *(uint4*)&sX[r * LDW + kc * 8] = v;
        }
    }
#pragma unroll
    for (int c = tid; c < COLS * 16; c += 256) {
        int r = c >> 4, kc = c & 15;
        uint4 v = *(const uint4*)&Wt[(size_t)r * 128 + kc * 8];
        *(uint4*)&sW[r * LDW + kc * 8] = v;
    }
    __syncthreads();

    constexpr int NT = (COLS == 128) ? 2 : 1;
    constexpr int WN = COLS / 4;
    const int w = tid >> 6;
    const int lane = tid & 63;
    const int lm = lane & 15;
    const int kq = lane >> 4;

    f32x4 acc[4][NT];
#pragma unroll
    for (int mt = 0; mt < 4; ++mt)
#pragma unroll
        for (int ntn = 0; ntn < NT; ++ntn) acc[mt][ntn] = (f32x4){0.f, 0.f, 0.f, 0.f};

#pragma unroll
    for (int ks = 0; ks < 4; ++ks) {
        const int k0 = ks * 32 + kq * 8;
        short8 bfr[NT];
#pragma unroll
        for (int ntn = 0; ntn < NT; ++ntn)
            bfr[ntn] = *(const short8*)&sW[(w * WN + ntn * 16 + lm) * LDW + k0];
#pragma unroll
        for (int mt = 0; mt < 4; ++mt) {
            short8 afr = *(const short8*)&sX[(mt * 16 + lm) * LDW + k0];
#pragma unroll
            for (int ntn = 0; ntn < NT; ++ntn)
                acc[mt][ntn] = __builtin_amdgcn_mfma_f32_16x16x32_bf16(afr, bfr[ntn], acc[mt][ntn], 0, 0, 0);
        }
    }

#pragma unroll
    for (int mt = 0; mt < 4; ++mt) {
        int r_base = row0 + mt * 16 + kq * 4;
#pragma unroll
        for (int ntn = 0; ntn < NT; ++ntn) {
            int col = w * WN + ntn * 16 + lm;
#pragma unroll
            for (int rr = 0; rr < 4; ++rr) {
                int r = r_base + rr;
                if (r < n) Y[(size_t)r * COLS + col] = f2bf(acc[mt][ntn][rr]);
            }
        }
    }
}

// ---------------------------------------------------------------------------
// Aggregation over bf16 H: out[v] = act( dv*(sum_e dis[s]*H[s] + dv*H[v]) + b )
// One wave/node; lane-parallel csr staging + inline dis gather; readlane
// broadcast; 16 independent row gathers in flight.
// ---------------------------------------------------------------------------
template <int COLS, bool RELU, bool NORM>
__global__ __launch_bounds__(256) void agg(const ushort* __restrict__ H,
                                           const float* __restrict__ dis,
                                           const int* __restrict__ rowptr,
                                           const int* __restrict__ csr,
                                           const float* __restrict__ bias,
                                           void* __restrict__ out, int n) {
    const int wid = blockIdx.x * 4 + (threadIdx.x >> 6);
    const int lane = threadIdx.x & 63;
    if (wid >= n) return;
    const int v = wid;
    const float dv = dis[v];
    const int e0 = rowptr[v];
    const int e1 = rowptr[v + 1];

    if (COLS == 128) {
        const uint* Hu = (const uint*)H;
        uint h0 = Hu[(size_t)v * 64 + lane];
        float ax = dv * bf_lo(h0), ay = dv * bf_hi(h0);

        int e = e0;
        while (e < e1) {
            const int c = min(e1 - e, 64);
            int sidx = 0; float sw = 0.0f;
            if (lane < c) { sidx = csr[e + lane]; sw = dis[sidx]; }
            int j = 0;
            for (; j + 16 <= c; j += 16) {
                uint hv[16]; float w[16];
#pragma unroll
                for (int u = 0; u < 16; ++u) {
                    int s = __builtin_amdgcn_readlane(sidx, j + u);
                    w[u] = lane_bcast_f(sw, j + u);
                    hv[u] = Hu[(size_t)s * 64 + lane];
                }
#pragma unroll
                for (int u = 0; u < 16; ++u) { ax += w[u] * bf_lo(hv[u]); ay += w[u] * bf_hi(hv[u]); }
            }
            for (; j + 4 <= c; j += 4) {
                uint hv[4]; float w[4];
#pragma unroll
                for (int u = 0; u < 4; ++u) {
                    int s = __builtin_amdgcn_readlane(sidx, j + u);
                    w[u] = lane_bcast_f(sw, j + u);
                    hv[u] = Hu[(size_t)s * 64 + lane];
                }
#pragma unroll
                for (int u = 0; u < 4; ++u) { ax += w[u] * bf_lo(hv[u]); ay += w[u] * bf_hi(hv[u]); }
            }
            for (; j < c; ++j) {
                int s = __builtin_amdgcn_readlane(sidx, j);
                float w = lane_bcast_f(sw, j);
                uint hh = Hu[(size_t)s * 64 + lane];
                ax += w * bf_lo(hh); ay += w * bf_hi(hh);
            }
            e += c;
        }

        float2 b = ((const float2*)bias)[lane];
        float rx = dv * ax + b.x;
        float ry = dv * ay + b.y;
        if (RELU) { rx = fmaxf(rx, 0.f); ry = fmaxf(ry, 0.f); }
        uint packed = (uint)f2bf(rx) | ((uint)f2bf(ry) << 16);
        ((uint*)out)[(size_t)v * 64 + lane] = packed;
    } else {
        float acc = dv * bf_lo((uint)H[(size_t)v * 64 + lane]);

        int e = e0;
        while (e < e1) {
            const int c = min(e1 - e, 64);
            int sidx = 0; float sw = 0.0f;
            if (lane < c) { sidx = csr[e + lane]; sw = dis[sidx]; }
            int j = 0;
            for (; j + 16 <= c; j += 16) {
                ushort hv[16]; float w[16];
#pragma unroll
                for (int u = 0; u < 16; ++u) {
                    int s = __builtin_amdgcn_readlane(sidx, j + u);
                    w[u] = lane_bcast_f(sw, j + u);
                    hv[u] = H[(size_t)s * 64 + lane];
                }
#pragma unroll
                for (int u = 0; u < 16; ++u) acc += w[u] * bf_lo((uint)hv[u]);
            }
            for (; j < c; ++j) {
                int s = __builtin_amdgcn_readlane(sidx, j);
                float w = lane_bcast_f(sw, j);
                acc += w * bf_lo((uint)H[(size_t)s * 64 + lane]);
            }
            e += c;
        }

        float r = dv * acc + bias[lane];
        if (RELU) r = fmaxf(r, 0.f);
        if (NORM) {
            float ss = r * r;
#pragma unroll
            for (int m = 1; m < 64; m <<= 1) ss += __shfl_xor(ss, m, 64);
            r = r / fmaxf(sqrtf(ss), 1e-12f);
        }
        ((float*)out)[(size_t)v * 64 + lane] = r;
    }
}

// ---------------------------------------------------------------------------
// Target branch
// ---------------------------------------------------------------------------
__global__ __launch_bounds__(256) void target_mlp(const float* __restrict__ y,
                                                  const float* __restrict__ gamma,
                                                  const float* __restrict__ beta,
                                                  const float* __restrict__ Wm1,
                                                  const float* __restrict__ bm1,
                                                  const float* __restrict__ Wm2,
                                                  const float* __restrict__ bm2,
                                                  float* __restrict__ out) {
    __shared__ float red[256];
    __shared__ float t1[128];
    __shared__ float s_mu, s_var;
    const int tid = threadIdx.x;
    float yv = y[tid];
    red[tid] = yv;
    __syncthreads();
    for (int s = 128; s > 0; s >>= 1) {
        if (tid < s) red[tid] += red[tid + s];
        __syncthreads();
    }
    if (tid == 0) s_mu = red[0] * (1.0f / 256.0f);
    __syncthreads();
    float mu = s_mu;
    float d = yv - mu;
    red[tid] = d * d;
    __syncthreads();
    for (int s = 128; s > 0; s >>= 1) {
        if (tid < s) red[tid] += red[tid + s];
        __syncthreads();
    }
    if (tid == 0) s_var = red[0] * (1.0f / 256.0f);
    __syncthreads();

    const int row = blockIdx.x;
    float yb = (y[row] - mu) * rsqrtf(s_var + 1e-5f) * gamma[0] + beta[0];
    if (tid < 128) t1[tid] = fmaxf(yb * Wm1[tid] + bm1[tid], 0.0f);
    __syncthreads();
    if (tid < 64) {
        float acc = bm2[tid];
#pragma unroll 8
        for (int c = 0; c < 128; ++c) acc += t1[c] * Wm2[c * 64 + tid];
        float ss = acc * acc;
#pragma unroll
        for (int m = 1; m < 64; m <<= 1) ss += __shfl_xor(ss, m, 64);
        out[row * 64 + tid] = acc / fmaxf(sqrtf(ss), 1e-12f);
    }
}

// ---------------------------------------------------------------------------
extern "C" void kernel_launch(void* const* d_in, const int* in_sizes, int n_in,
                              void* d_out, int out_size, void* d_ws, size_t ws_size,
                              hipStream_t stream) {
    const float* x     = (const float*)d_in[0];
    const float* y     = (const float*)d_in[1];
    const int*   edge  = (const int*)d_in[2];
    const float* W1    = (const float*)d_in[3];
    const float* b1    = (const float*)d_in[4];
    const float* W2    = (const float*)d_in[5];
    const float* b2    = (const float*)d_in[6];
    const float* W3    = (const float*)d_in[7];
    const float* b3    = (const float*)d_in[8];
    const float* bng   = (const float*)d_in[9];
    const float* bnb   = (const float*)d_in[10];
    const float* Wm1   = (const float*)d_in[11];
    const float* bm1   = (const float*)d_in[12];
    const float* Wm2   = (const float*)d_in[13];
    const float* bm2   = (const float*)d_in[14];

    const int n = in_sizes[0] / 128;  // 50000
    const int E = in_sizes[2] / 2;    // 800000
    const int* src = edge;
    const int* dst = edge + E;

    const int nbuck = (n + 255) / 256;                 // 196
    const int cap = E / nbuck + E / nbuck / 4 + 1024;  // mean + 25% + slack

    size_t off = 0;
    auto carve = [&](size_t bytes) {
        size_t p = off;
        off = (off + bytes + 255) & ~(size_t)255;
        return p;
    };
    char* ws = (char*)d_ws;
    int*    gcur    = (int*)(ws + carve(256 * 4));
    uint*   part    = (uint*)(ws + carve((size_t)nbuck * cap * 4));
    int*    rowptr  = (int*)(ws + carve((size_t)(n + 1) * 4));
    int*    csr     = (int*)(ws + carve((size_t)E * 4));
    float*  dis     = (float*)(ws + carve((size_t)n * 4));
    ushort* wt1     = (ushort*)(ws + carve(128 * 128 * 2));
    ushort* wt2     = (ushort*)(ws + carve(128 * 128 * 2));
    ushort* wt3     = (ushort*)(ws + carve(64 * 128 * 2));
    ushort* bufA    = (ushort*)(ws + carve((size_t)n * 128 * 2));
    ushort* bufB    = (ushort*)(ws + carve((size_t)n * 128 * 2));
    ushort* bufC    = (ushort*)(ws + carve((size_t)n * 64 * 2));
    (void)ws_size; (void)n_in; (void)out_size;

    float* x_emb = (float*)d_out;
    float* y_emb = (float*)d_out + (size_t)n * 64;

    hipMemsetAsync(gcur, 0, 256 * 4, stream);
    k_partition<<<(E + PCHUNK - 1) / PCHUNK, 256, 0, stream>>>(src, dst, E, nbuck, cap, gcur, part);
    k_bucket_sort<<<nbuck, 256, 0, stream>>>(part, gcur, nbuck, cap, n, rowptr, dis, csr);
    k_wcast3<<<160, 256, 0, stream>>>(W1, W2, W3, wt1, wt2, wt3);

    const int ggrid = (n + 63) / 64;
    const int agrid = (n + 3) / 4;

    gemm_mfma<128, true><<<ggrid, 256, 0, stream>>>(x, wt1, bufA, n);
    agg<128, true, false><<<agrid, 256, 0, stream>>>(bufA, dis, rowptr, csr, b1, bufB, n);
    gemm_mfma<128, false><<<ggrid, 256, 0, stream>>>(bufB, wt2, bufA, n);
    agg<128, true, false><<<agrid, 256, 0, stream>>>(bufA, dis, rowptr, csr, b2, bufB, n);
    gemm_mfma<64, false><<<ggrid, 256, 0, stream>>>(bufB, wt3, bufC, n);
    agg<64, false, true><<<agrid, 256, 0, stream>>>(bufC, dis, rowptr, csr, b3, x_emb, n);

    target_mlp<<<256, 256, 0, stream>>>(y, bng, bnb, Wm1, bm1, Wm2, bm2, y_emb);
}